// Round 1
// baseline (151.536 us; speedup 1.0000x reference)
//
#include <hip/hip_runtime.h>

#define N_PARTS 62
#define M_SAMP  512
#define D_DIM   256
#define MARGIN  0.2f

typedef unsigned short ushort_t;
typedef __attribute__((ext_vector_type(8))) short bf16x8;   // 8 bf16 = 4 VGPRs
typedef __attribute__((ext_vector_type(4))) float f32x4;

__device__ __forceinline__ ushort_t bf16_rne(float f) {
    unsigned u = __float_as_uint(f);
    unsigned r = u + 0x7fffu + ((u >> 16) & 1u);
    return (ushort_t)(r >> 16);
}

// Swizzled LDS offset (in shorts) of 16B slot q (0..3) of row (0..511).
// tile row = 64 B = 4 slots; q ^= (row>>1)&3 makes the 16-lane frag-read
// groups (rows r0..r0+15, fixed q) start at banks {0,16,4,20,8,24,12,28}:
// exact 2-lane/bank coverage for ds_read_b128 (conflict-free).
__device__ __forceinline__ int lds_off(int row, int q) {
    return row * 32 + ((q ^ ((row >> 1) & 3)) << 3);
}

__global__ void zero_out_kernel(float* __restrict__ out) {
    if (threadIdx.x < 2 * N_PARTS) out[threadIdx.x] = 0.0f;
}

// Single fused kernel: stages the part's fp32 rows chunk-by-chunk into a
// double-buffered swizzled bf16 LDS tile (conversion + row sum-of-squares
// in the same pass), runs the 64x128-per-wave MFMA gram, then the verified
// R12 epilogue. No global bf16 intermediate, no second kernel.
__global__ __launch_bounds__(512, 2) void fused_all_kernel(
        const float* __restrict__ feat, float* __restrict__ out) {
    const int id = blockIdx.x;
    const int n  = id & 63;          // part (XCD affinity: id%8 == n%8)
    const int ct = id >> 6;          // col-slab (128 cols)
    if (n >= N_PARTS) return;
    const int tid  = threadIdx.x;
    const int wave = tid >> 6, lane = tid & 63;

    __shared__ ushort_t tile[2][512 * 32];   // 2 x 32 KB bf16, swizzled
    __shared__ float sqA[M_SAMP];            // per-row sum-of-squares (rounded vals)
    __shared__ float mrg[8][128][3];         // [wave][slab-local col][hp,hn,ds]

    const int r8 = tid >> 3;                 // row within 64-row group
    const int k4 = tid & 7;                  // float4 column quad
    const float* fb = feat + (size_t)n * (M_SAMP * D_DIM) + (size_t)k4 * 4;

    f32x4 acc[4][8] = {};
    float sqp[8] = {0.f, 0.f, 0.f, 0.f, 0.f, 0.f, 0.f, 0.f};

    // ---- prologue: stage chunk 0 into buf 0
    #pragma unroll
    for (int i = 0; i < 8; ++i) {
        const int row = i * 64 + r8;
        const float4 v = *(const float4*)(fb + (size_t)row * D_DIM);
        ushort4 us;
        us.x = bf16_rne(v.x); us.y = bf16_rne(v.y);
        us.z = bf16_rne(v.z); us.w = bf16_rne(v.w);
        const float fx = __uint_as_float((unsigned)us.x << 16);
        const float fy = __uint_as_float((unsigned)us.y << 16);
        const float fz = __uint_as_float((unsigned)us.z << 16);
        const float fw = __uint_as_float((unsigned)us.w << 16);
        sqp[i] += fx * fx + fy * fy + fz * fz + fw * fw;
        *(ushort4*)(&tile[0][lds_off(row, k4 >> 1) + (k4 & 1) * 4]) = us;
    }
    __syncthreads();

    // ---- main loop: prefetch chunk c+1 (global->reg), MFMA chunk c (LDS),
    //      convert+write chunk c+1 into the other buffer.
    #pragma unroll
    for (int c = 0; c < 8; ++c) {
        float4 nx[8];
        if (c < 7) {
            #pragma unroll
            for (int i = 0; i < 8; ++i)
                nx[i] = *(const float4*)(fb + (size_t)(i * 64 + r8) * D_DIM
                                            + (size_t)(c + 1) * 32);
        }
        const ushort_t* tb = tile[c & 1];
        bf16x8 af[4], bf[8];
        #pragma unroll
        for (int i = 0; i < 4; ++i)
            af[i] = *(const bf16x8*)(tb + lds_off(wave * 64 + i * 16 + (lane & 15),
                                                  lane >> 4));
        #pragma unroll
        for (int i = 0; i < 8; ++i)
            bf[i] = *(const bf16x8*)(tb + lds_off(ct * 128 + i * 16 + (lane & 15),
                                                  lane >> 4));
        #pragma unroll
        for (int mi = 0; mi < 4; ++mi)
            #pragma unroll
            for (int ni = 0; ni < 8; ++ni)
                acc[mi][ni] = __builtin_amdgcn_mfma_f32_16x16x32_bf16(
                    af[mi], bf[ni], acc[mi][ni], 0, 0, 0);
        if (c < 7) {
            ushort_t* tn = tile[(c + 1) & 1];
            #pragma unroll
            for (int i = 0; i < 8; ++i) {
                const int row = i * 64 + r8;
                ushort4 us;
                us.x = bf16_rne(nx[i].x); us.y = bf16_rne(nx[i].y);
                us.z = bf16_rne(nx[i].z); us.w = bf16_rne(nx[i].w);
                const float fx = __uint_as_float((unsigned)us.x << 16);
                const float fy = __uint_as_float((unsigned)us.y << 16);
                const float fz = __uint_as_float((unsigned)us.z << 16);
                const float fw = __uint_as_float((unsigned)us.w << 16);
                sqp[i] += fx * fx + fy * fy + fz * fz + fw * fw;
                *(ushort4*)(&tn[lds_off(row, k4 >> 1) + (k4 & 1) * 4]) = us;
            }
        }
        __syncthreads();
    }

    // ---- finalize row sum-of-squares: reduce the 8 k4-partials per row
    #pragma unroll
    for (int i = 0; i < 8; ++i) {
        float s = sqp[i];
        s += __shfl_xor(s, 1);
        s += __shfl_xor(s, 2);
        s += __shfl_xor(s, 4);
        if (k4 == 0) sqA[i * 64 + r8] = s;
    }
    __syncthreads();

    // ---- epilogue: identical to verified R12, SQ reads from LDS sqA.
    // C/D layout: col = lane&15, row = (lane>>4)*4 + reg.
    float sqr[4][4];
    #pragma unroll
    for (int mi = 0; mi < 4; ++mi)
        #pragma unroll
        for (int p = 0; p < 4; ++p)
            sqr[mi][p] = sqA[wave * 64 + mi * 16 + (lane >> 4) * 4 + p];

    #pragma unroll
    for (int ni = 0; ni < 8; ++ni) {
        const int C = ct * 128 + ni * 16 + (lane & 15);   // part-local col
        const float sc = sqA[C];
        const int Cg = C >> 3;                             // label = m>>3
        float ds = 0.f, hp = 0.f, hn = 1e30f;
        #pragma unroll
        for (int mi = 0; mi < 4; ++mi) {
            #pragma unroll
            for (int p = 0; p < 4; ++p) {
                const int R = wave * 64 + mi * 16 + (lane >> 4) * 4 + p;
                const float d2 = sqr[mi][p] + sc - 2.f * acc[mi][ni][p];
                const float d  = __builtin_amdgcn_sqrtf(fmaxf(d2, 0.f));
                ds += d;
                if ((R >> 3) == Cg) hp = fmaxf(hp, d);
                else                hn = fminf(hn, d);
            }
        }
        #pragma unroll
        for (int off = 16; off < 64; off <<= 1) {
            ds += __shfl_xor(ds, off);
            hp = fmaxf(hp, __shfl_xor(hp, off));
            hn = fminf(hn, __shfl_xor(hn, off));
        }
        if (lane < 16) {
            mrg[wave][ni * 16 + lane][0] = hp;
            mrg[wave][ni * 16 + lane][1] = hn;
            mrg[wave][ni * 16 + lane][2] = ds;
        }
    }
    __syncthreads();
    if (tid < 128) {   // col tid of the slab: merge 8 row-strips
        float hp = 0.f, hn = 1e30f, bd = 0.f;
        #pragma unroll
        for (int w = 0; w < 8; ++w) {
            hp = fmaxf(hp, mrg[w][tid][0]);
            hn = fminf(hn, mrg[w][tid][1]);
            bd += mrg[w][tid][2];
        }
        const float bl = fmaxf(MARGIN + hp - hn, 0.f);
        mrg[0][tid][0] = bl;
        mrg[0][tid][1] = bd;
    }
    __syncthreads();
    if (tid < 64) {
        float bl = mrg[0][tid][0] + mrg[0][tid + 64][0];
        float bd = mrg[0][tid][1] + mrg[0][tid + 64][1];
        #pragma unroll
        for (int off = 32; off > 0; off >>= 1) {
            bl += __shfl_xor(bl, off);
            bd += __shfl_xor(bd, off);
        }
        if (lane == 0) {
            atomicAdd(&out[n],           bl * (1.0f / 512.0f));
            atomicAdd(&out[N_PARTS + n], bd * (1.0f / (512.0f * 512.0f)));
        }
    }
}

extern "C" void kernel_launch(void* const* d_in, const int* in_sizes, int n_in,
                              void* d_out, int out_size, void* d_ws, size_t ws_size,
                              hipStream_t stream) {
    const float* feat = (const float*)d_in[0];    // [62, 512, 256] fp32
    float* out = (float*)d_out;                   // [124]
    (void)d_ws; (void)ws_size;                    // no workspace needed anymore

    zero_out_kernel<<<dim3(1), 128, 0, stream>>>(out);
    fused_all_kernel<<<dim3(4 * 64), 512, 0, stream>>>(feat, out);
}

// Round 2
// 149.810 us; speedup vs baseline: 1.0115x; 1.0115x over previous
//
#include <hip/hip_runtime.h>

#define N_PARTS 62
#define M_SAMP  512
#define D_DIM   256
#define MARGIN  0.2f

typedef unsigned short ushort_t;
typedef __attribute__((ext_vector_type(8))) short bf16x8;   // 8 bf16 = 4 VGPRs
typedef __attribute__((ext_vector_type(4))) float f32x4;

__device__ __forceinline__ ushort_t bf16_rne(float f) {
    unsigned u = __float_as_uint(f);
    unsigned r = u + 0x7fffu + ((u >> 16) & 1u);
    return (ushort_t)(r >> 16);
}

// Swizzled LDS offset (in shorts) of 16B slot q (0..3) of row (0..511).
// tile row = 64 B = 4 slots; q ^= (row>>1)&3 makes the 16-lane frag-read
// groups (rows r0..r0+15, fixed q) start at banks {0,16,4,20,8,24,12,28}:
// exact 2-lane/bank coverage for ds_read_b128 (conflict-free).
__device__ __forceinline__ int lds_off(int row, int q) {
    return row * 32 + ((q ^ ((row >> 1) & 3)) << 3);
}

__global__ void zero_out_kernel(float* __restrict__ out) {
    if (threadIdx.x < 2 * N_PARTS) out[threadIdx.x] = 0.0f;
}

// Fused kernel, spill-free revision.
// R1 post-mortem: __launch_bounds__(512,2) + acc[4][8]+af[4]+bf[8]+nx[8]
// demanded ~220 regs against a 128 arch-VGPR cap -> 96 MB/dispatch scratch
// spill (WRITE_SIZE), MfmaUtil 3.4%. Fix: no min-waves bound (feasibility
// cap = 256 for a 512-thread block; LDS 78 KB already limits to 1 block/CU
// so high VGPR use is free) + stream B fragments (live 8 regs, not 32).
__global__ __launch_bounds__(512) void fused_all_kernel(
        const float* __restrict__ feat, float* __restrict__ out) {
    const int id = blockIdx.x;
    const int n  = id & 63;          // part (XCD affinity: id%8 == n%8)
    const int ct = id >> 6;          // col-slab (128 cols)
    if (n >= N_PARTS) return;
    const int tid  = threadIdx.x;
    const int wave = tid >> 6, lane = tid & 63;

    __shared__ ushort_t tile[2][512 * 32];   // 2 x 32 KB bf16, swizzled
    __shared__ float sqA[M_SAMP];            // per-row sum-of-squares (rounded vals)
    __shared__ float mrg[8][128][3];         // [wave][slab-local col][hp,hn,ds]

    const int r8 = tid >> 3;                 // row within 64-row group
    const int k4 = tid & 7;                  // float4 column quad
    const float* fb = feat + (size_t)n * (M_SAMP * D_DIM) + (size_t)k4 * 4;

    f32x4 acc[4][8] = {};
    float sqp[8] = {0.f, 0.f, 0.f, 0.f, 0.f, 0.f, 0.f, 0.f};

    // ---- prologue: stage chunk 0 into buf 0
    #pragma unroll
    for (int i = 0; i < 8; ++i) {
        const int row = i * 64 + r8;
        const float4 v = *(const float4*)(fb + (size_t)row * D_DIM);
        ushort4 us;
        us.x = bf16_rne(v.x); us.y = bf16_rne(v.y);
        us.z = bf16_rne(v.z); us.w = bf16_rne(v.w);
        const float fx = __uint_as_float((unsigned)us.x << 16);
        const float fy = __uint_as_float((unsigned)us.y << 16);
        const float fz = __uint_as_float((unsigned)us.z << 16);
        const float fw = __uint_as_float((unsigned)us.w << 16);
        sqp[i] += fx * fx + fy * fy + fz * fz + fw * fw;
        *(ushort4*)(&tile[0][lds_off(row, k4 >> 1) + (k4 & 1) * 4]) = us;
    }
    __syncthreads();

    // ---- main loop: prefetch chunk c+1 (global->reg), MFMA chunk c (LDS),
    //      convert+write chunk c+1 into the other buffer.
    #pragma unroll
    for (int c = 0; c < 8; ++c) {
        float4 nx[8];
        if (c < 7) {
            #pragma unroll
            for (int i = 0; i < 8; ++i)
                nx[i] = *(const float4*)(fb + (size_t)(i * 64 + r8) * D_DIM
                                            + (size_t)(c + 1) * 32);
        }
        const ushort_t* tb = tile[c & 1];
        bf16x8 af[4];
        #pragma unroll
        for (int i = 0; i < 4; ++i)
            af[i] = *(const bf16x8*)(tb + lds_off(wave * 64 + i * 16 + (lane & 15),
                                                  lane >> 4));
        // stream B fragments: one live bf at a time (8 regs vs 32)
        #pragma unroll
        for (int ni = 0; ni < 8; ++ni) {
            const bf16x8 bfv = *(const bf16x8*)(tb + lds_off(ct * 128 + ni * 16 + (lane & 15),
                                                             lane >> 4));
            #pragma unroll
            for (int mi = 0; mi < 4; ++mi)
                acc[mi][ni] = __builtin_amdgcn_mfma_f32_16x16x32_bf16(
                    af[mi], bfv, acc[mi][ni], 0, 0, 0);
        }
        if (c < 7) {
            ushort_t* tn = tile[(c + 1) & 1];
            #pragma unroll
            for (int i = 0; i < 8; ++i) {
                const int row = i * 64 + r8;
                ushort4 us;
                us.x = bf16_rne(nx[i].x); us.y = bf16_rne(nx[i].y);
                us.z = bf16_rne(nx[i].z); us.w = bf16_rne(nx[i].w);
                const float fx = __uint_as_float((unsigned)us.x << 16);
                const float fy = __uint_as_float((unsigned)us.y << 16);
                const float fz = __uint_as_float((unsigned)us.z << 16);
                const float fw = __uint_as_float((unsigned)us.w << 16);
                sqp[i] += fx * fx + fy * fy + fz * fz + fw * fw;
                *(ushort4*)(&tn[lds_off(row, k4 >> 1) + (k4 & 1) * 4]) = us;
            }
        }
        __syncthreads();
    }

    // ---- finalize row sum-of-squares: reduce the 8 k4-partials per row
    #pragma unroll
    for (int i = 0; i < 8; ++i) {
        float s = sqp[i];
        s += __shfl_xor(s, 1);
        s += __shfl_xor(s, 2);
        s += __shfl_xor(s, 4);
        if (k4 == 0) sqA[i * 64 + r8] = s;
    }
    __syncthreads();

    // ---- epilogue: identical to verified R12, SQ reads from LDS sqA.
    // C/D layout: col = lane&15, row = (lane>>4)*4 + reg.
    float sqr[4][4];
    #pragma unroll
    for (int mi = 0; mi < 4; ++mi)
        #pragma unroll
        for (int p = 0; p < 4; ++p)
            sqr[mi][p] = sqA[wave * 64 + mi * 16 + (lane >> 4) * 4 + p];

    #pragma unroll
    for (int ni = 0; ni < 8; ++ni) {
        const int C = ct * 128 + ni * 16 + (lane & 15);   // part-local col
        const float sc = sqA[C];
        const int Cg = C >> 3;                             // label = m>>3
        float ds = 0.f, hp = 0.f, hn = 1e30f;
        #pragma unroll
        for (int mi = 0; mi < 4; ++mi) {
            #pragma unroll
            for (int p = 0; p < 4; ++p) {
                const int R = wave * 64 + mi * 16 + (lane >> 4) * 4 + p;
                const float d2 = sqr[mi][p] + sc - 2.f * acc[mi][ni][p];
                const float d  = __builtin_amdgcn_sqrtf(fmaxf(d2, 0.f));
                ds += d;
                if ((R >> 3) == Cg) hp = fmaxf(hp, d);
                else                hn = fminf(hn, d);
            }
        }
        #pragma unroll
        for (int off = 16; off < 64; off <<= 1) {
            ds += __shfl_xor(ds, off);
            hp = fmaxf(hp, __shfl_xor(hp, off));
            hn = fminf(hn, __shfl_xor(hn, off));
        }
        if (lane < 16) {
            mrg[wave][ni * 16 + lane][0] = hp;
            mrg[wave][ni * 16 + lane][1] = hn;
            mrg[wave][ni * 16 + lane][2] = ds;
        }
    }
    __syncthreads();
    if (tid < 128) {   // col tid of the slab: merge 8 row-strips
        float hp = 0.f, hn = 1e30f, bd = 0.f;
        #pragma unroll
        for (int w = 0; w < 8; ++w) {
            hp = fmaxf(hp, mrg[w][tid][0]);
            hn = fminf(hn, mrg[w][tid][1]);
            bd += mrg[w][tid][2];
        }
        const float bl = fmaxf(MARGIN + hp - hn, 0.f);
        mrg[0][tid][0] = bl;
        mrg[0][tid][1] = bd;
    }
    __syncthreads();
    if (tid < 64) {
        float bl = mrg[0][tid][0] + mrg[0][tid + 64][0];
        float bd = mrg[0][tid][1] + mrg[0][tid + 64][1];
        #pragma unroll
        for (int off = 32; off > 0; off >>= 1) {
            bl += __shfl_xor(bl, off);
            bd += __shfl_xor(bd, off);
        }
        if (lane == 0) {
            atomicAdd(&out[n],           bl * (1.0f / 512.0f));
            atomicAdd(&out[N_PARTS + n], bd * (1.0f / (512.0f * 512.0f)));
        }
    }
}

extern "C" void kernel_launch(void* const* d_in, const int* in_sizes, int n_in,
                              void* d_out, int out_size, void* d_ws, size_t ws_size,
                              hipStream_t stream) {
    const float* feat = (const float*)d_in[0];    // [62, 512, 256] fp32
    float* out = (float*)d_out;                   // [124]
    (void)d_ws; (void)ws_size;                    // no workspace needed

    zero_out_kernel<<<dim3(1), 128, 0, stream>>>(out);
    fused_all_kernel<<<dim3(4 * 64), 512, 0, stream>>>(feat, out);
}